// Round 5
// baseline (291.852 us; speedup 1.0000x reference)
//
#include <hip/hip_runtime.h>
#include <math.h>

// EuclideanCodebook: N=131072 rows x d=128 fp32, K=1024 codes.
// bf16x2 split-precision MFMA (xh*eh + xl*eh), per-row top-2 gap tracking,
// exact fp32 recheck of rows with gap < TAU.
// R2/R8: 64 rows/wave -> 260 VGPR -> spills (WRITE +48GB). 32 rows/wave only.
// R3: dynamic ah[s] indexing -> cndmask waterfall. Fixed: full s-unroll.
// R5: 141 us. R6: no-LDS B loads regressed (no prefetch distance).
// R7: counted vmcnt + raw barriers. 156 us. Pipe inventory: MFMA 41 us,
//     LDS-read 41 us, VALU 57 us (epilogue 6 ops/score = 41 us of it).
// R9: attack all three pipes algorithmically.
//     (a) bf16x2: drop xh*el term + elo buffer. Score err sigma ~0.026 ->
//         TAU 0.25 (10 sigma). MFMA 41->27 us, LDS 41->20.5 us, recheck
//         ~3.5% of rows (exact fp32, fused tail).
//     (b) single merged MFMA chain, C=0 folded into first MFMA (no acc-init
//         movs, no accA+accB add) + v_med3_f32 top-2: 6 -> 4 VALU/score.
//     (c) one barrier/tile: 3 LDS buffers, depth-2 prefetch, vmcnt(2).
//     (d) launch_bounds(256,2): ~150 VGPR, spill-proof.
// R9b (this round): identical resubmit -- R9 bench died to container-infra
//     failure (no compile/validation error); audit found no hang/fault path.

typedef __attribute__((ext_vector_type(8)))  short short8_t;   // 8 bf16
typedef __attribute__((ext_vector_type(16))) float floatx16;   // 32x32 C frag

constexpr int D        = 128;
constexpr int KCODES   = 1024;
constexpr int NTILES   = 32;      // 1024 / 32 codes-per-tile
constexpr int ROWS_BLK = 128;     // 4 waves x 32 rows
constexpr float TAU    = 0.25f;   // ~10 sigma of bf16x2 score error (0.026)

// ws layout (bytes); total ~0.77 MB
constexpr size_t WS_NCSQ = 0;                      // 1024 f32, NEGATED ||e||^2
constexpr size_t WS_EHI  = 4096;                   // 1024*128 ushort, frag-ordered
constexpr size_t WS_EMBT = WS_EHI + 262144;        // 128*1024 f32 transposed

#define GLOBAL_AS __attribute__((address_space(1)))
#define LDS_AS    __attribute__((address_space(3)))

__device__ inline unsigned short bf16_rne(float v, float* back) {
    unsigned u = __float_as_uint(v);
    unsigned r = (u + 0x7FFFu + ((u >> 16) & 1u)) >> 16;
    *back = __uint_as_float(r << 16);
    return (unsigned short)r;
}

// ------- prep: ncsq + frag-ordered bf16 hi codebook + transposed codebook ----
// 64 blocks x 256 threads; thread = (code n, dim-chunk cc of 8 elements).
// Frag order: short8 chunk index = (t*8 + (cc>>1))*64 + (cc&1)*32 + (n&31),
// so main's lane l reads tile t, MFMA-step s at short8 index (t*8+s)*64 + l.
__global__ __launch_bounds__(256)
void ecb_prep(const float* __restrict__ embed, float* __restrict__ ncsq,
              unsigned short* __restrict__ ehi, float* __restrict__ embT) {
    const int tid = threadIdx.x;
    const int cc = tid & 15;            // dim chunk 0..15
    const int nl = tid >> 4;            // 0..15
    const int n  = blockIdx.x * 16 + nl;
    const int t = n >> 5, nn = n & 31;
    const float* src = embed + (size_t)n * D + cc * 8;
    float4 a = *(const float4*)src;
    float4 b = *(const float4*)(src + 4);
    float vv[8] = {a.x, a.y, a.z, a.w, b.x, b.y, b.z, b.w};
    float ss = 0.f;
    unsigned short hq[8];
#pragma unroll
    for (int j = 0; j < 8; ++j) {
        ss = fmaf(vv[j], vv[j], ss);
        float hb;
        hq[j] = bf16_rne(vv[j], &hb);
    }
    uint4 ph;
    ph.x = (unsigned)hq[0] | ((unsigned)hq[1] << 16);
    ph.y = (unsigned)hq[2] | ((unsigned)hq[3] << 16);
    ph.z = (unsigned)hq[4] | ((unsigned)hq[5] << 16);
    ph.w = (unsigned)hq[6] | ((unsigned)hq[7] << 16);
    size_t dst = ((size_t)(t * 8 + (cc >> 1)) * 64 + (size_t)((cc & 1) * 32 + nn)) * 8;
    *(uint4*)(ehi + dst) = ph;
#pragma unroll
    for (int j = 0; j < 8; ++j) embT[(size_t)(cc * 8 + j) * KCODES + n] = vv[j];
    // csq reduce over the 16 cc-lanes (contiguous within the wave)
#pragma unroll
    for (int m = 1; m < 16; m <<= 1) ss += __shfl_xor(ss, m, 64);
    if (cc == 0) ncsq[n] = -ss;
}

// ---------------- main: MFMA scores + argmax + fused exact recheck ----------------
__global__ __launch_bounds__(256, 2)
void ecb_main(const float* __restrict__ x,
              const unsigned short* __restrict__ ehi,
              const float* __restrict__ ncsq, const float* __restrict__ embed,
              const float* __restrict__ embT,
              float* __restrict__ out_idx, float* __restrict__ out_q) {
    __shared__ short8_t ebuf[3][512];      // 3 bufs x 8 KB (hi only), 24 KB
    __shared__ float ncsq_s[KCODES];       // 4 KB
    __shared__ int   sidx[ROWS_BLK];
    __shared__ unsigned char llist[ROWS_BLK];
    __shared__ unsigned lcount;

    const int tid  = threadIdx.x;
    const int lane = tid & 63, wave = tid >> 6;
    const int col  = lane & 31, h = lane >> 5;
    const long rowblk = (long)blockIdx.x * ROWS_BLK;
    const int  roww   = wave * 32;

    if (tid == 0) lcount = 0u;

    auto stage = [&](int t, int bs) {
        const char* gh = (const char*)ehi + (size_t)t * 8192;
        char* lh = (char*)&ebuf[bs][0];
        const int off = wave * 2048;
        // 2 x global_load_lds_dwordx4 per wave = the vmcnt quantum per stage
        __builtin_amdgcn_global_load_lds((const GLOBAL_AS unsigned int*)(gh + off + lane * 16),
                                         (LDS_AS unsigned int*)(lh + off), 16, 0, 0);
        __builtin_amdgcn_global_load_lds((const GLOBAL_AS unsigned int*)(gh + off + 1024 + lane * 16),
                                         (LDS_AS unsigned int*)(lh + off + 1024), 16, 0, 0);
    };

    stage(0, 0);                           // depth-2 prefetch, issued ASAP
    stage(1, 1);
    ((float4*)ncsq_s)[tid] = ((const float4*)ncsq)[tid];   // 1024 f32 -> LDS

    // A prologue: 32 rows/wave of x -> bf16 hi/lo split of (2*x) in registers.
    short8_t ah[8], al[8];
    {
        const float* xr = x + (rowblk + roww + col) * (long)D + h * 8;
#pragma unroll
        for (int c = 0; c < 8; ++c) {
            float4 a  = *(const float4*)(xr + c * 16);
            float4 b  = *(const float4*)(xr + c * 16 + 4);
            float vv[8] = {a.x, a.y, a.z, a.w, b.x, b.y, b.z, b.w};
            short8_t fh, fl;
#pragma unroll
            for (int j = 0; j < 8; ++j) {
                float v2x = vv[j] + vv[j];    // fold the score's factor-2 into A
                float hb, db;
                fh[j] = (short)bf16_rne(v2x, &hb);
                fl[j] = (short)bf16_rne(v2x - hb, &db);
            }
            ah[c] = fh;
            al[c] = fl;
        }
    }

    float v1[16], v2[16];
#pragma unroll
    for (int j = 0; j < 16; ++j) { v1[j] = -INFINITY; v2[j] = -INFINITY; }

    // ncsq_s/lcount visible; stage loads stay in flight (lgkm only)
    asm volatile("s_waitcnt lgkmcnt(0)" ::: "memory");
    __builtin_amdgcn_sched_barrier(0);
    __builtin_amdgcn_s_barrier();

#pragma unroll 1
    for (int t = 0; t < NTILES; ++t) {
        // stage(t) landed (stage(t+1)'s 2 loads may remain in flight)
        if (t + 1 < NTILES) asm volatile("s_waitcnt vmcnt(2)" ::: "memory");
        else                asm volatile("s_waitcnt vmcnt(0)" ::: "memory");
        __builtin_amdgcn_sched_barrier(0);
        // one barrier/tile: buf[t%3] ready for all waves AND all waves'
        // ds_reads of buf[(t-1)%3] are complete (consumed by their MFMAs
        // before program order reached this barrier).
        __builtin_amdgcn_s_barrier();
        if (t + 2 < NTILES) stage(t + 2, (t + 2) % 3);   // overwrites (t-1)%3: safe

        const int bs = t % 3;
        const float negcs = ncsq_s[t * 32 + col];        // LDS, conflict-free

        floatx16 acc;                                    // C=0 folds into MFMA #1
#pragma unroll
        for (int i = 0; i < 16; ++i) acc[i] = 0.f;

        __builtin_amdgcn_s_setprio(1);
#pragma unroll
        for (int s = 0; s < 8; ++s) {
            short8_t bh = ebuf[bs][s * 64 + lane];       // ds_read_b128, 1KB/wave
            acc = __builtin_amdgcn_mfma_f32_32x32x16_bf16(ah[s], bh, acc, 0, 0, 0);
            acc = __builtin_amdgcn_mfma_f32_32x32x16_bf16(al[s], bh, acc, 0, 0, 0);
        }
        __builtin_amdgcn_s_setprio(0);

        // epilogue: 4 VALU/score = add, tag(and_or), max, med3
#pragma unroll
        for (int j = 0; j < 16; ++j) {
            float sc = acc[j] + negcs;                   // 2 x.e - ||e||^2
            unsigned u = (__float_as_uint(sc) & ~31u) | (unsigned)t;
            float cand = __uint_as_float(u);
            float vo = v1[j];
            v1[j] = fmaxf(vo, cand);
            v2[j] = __builtin_amdgcn_fmed3f(vo, v2[j], cand);  // 2nd-best
        }
    }

    // cross-lane top-2 merge over the 32 columns of each half
#pragma unroll
    for (int j = 0; j < 16; ++j) {
        float a1 = v1[j], a2 = v2[j];
        int   c1 = (int)((__float_as_uint(a1) & 31u) << 5) | col;   // tile*32 + col
#pragma unroll
        for (int m = 1; m < 32; m <<= 1) {
            float o1 = __shfl_xor(a1, m, 64);
            int   oc = __shfl_xor(c1, m, 64);
            float o2 = __shfl_xor(a2, m, 64);
            float lo = fminf(a1, o1);
            if (o1 > a1) { a1 = o1; c1 = oc; }
            a2 = fmaxf(fmaxf(a2, o2), lo);
        }
        if (col == j) {
            int row_local = roww + (j & 3) + 8 * (j >> 2) + 4 * h;
            sidx[row_local] = c1;
            out_idx[rowblk + row_local] = (float)c1;
            if (a1 - a2 < TAU) {                      // ties always land here
                unsigned p = atomicAdd(&lcount, 1u);  // <= 128 by construction
                llist[p] = (unsigned char)row_local;
            }
        }
    }
    __syncthreads();

    // gather quantize = embed[best] (exact fp32 values, L2-hot)
    for (int i = tid; i < ROWS_BLK * 32; i += 256) {
        int r = i >> 5, q = i & 31;
        int code = sidx[r];
        float4 ev = *(const float4*)(embed + (size_t)code * D + q * 4);
        *(float4*)(out_q + (rowblk + r) * (long)D + q * 4) = ev;
    }
    __syncthreads();

    // fused exact fp32 recheck of this block's flagged rows (k-sequential
    // accumulation order). Scratch aliases ebuf (loop is done).
    float* xs = (float*)&ebuf[0][0];              // 128 f32
    float* bv = xs + D;                           // 256 f32
    int*   bi = (int*)(bv + 256);                 // 256 i32
    const unsigned nf = lcount;
    const float4* eT = (const float4*)embT;       // [k][256 x float4-of-codes]
    for (unsigned f = 0; f < nf; ++f) {
        const int rl  = llist[f];
        const long row = rowblk + rl;
        if (tid < 32) *(float4*)&xs[tid * 4] = *(const float4*)(x + row * D + tid * 4);
        __syncthreads();
        float4 dot = {0.f, 0.f, 0.f, 0.f};
#pragma unroll 8
        for (int k = 0; k < D; ++k) {
            float xv = xs[k];
            float4 e = eT[(size_t)k * 256 + tid];
            dot.x = fmaf(xv, e.x, dot.x);
            dot.y = fmaf(xv, e.y, dot.y);
            dot.z = fmaf(xv, e.z, dot.z);
            dot.w = fmaf(xv, e.w, dot.w);
        }
        const int c0 = tid * 4;
        float scs[4] = {fmaf(2.f, dot.x, ncsq_s[c0]),
                        fmaf(2.f, dot.y, ncsq_s[c0 + 1]),
                        fmaf(2.f, dot.z, ncsq_s[c0 + 2]),
                        fmaf(2.f, dot.w, ncsq_s[c0 + 3])};
        float best = -INFINITY; int bidx = 0;
#pragma unroll
        for (int i = 0; i < 4; ++i)
            if (scs[i] > best) { best = scs[i]; bidx = c0 + i; }
        bv[tid] = best; bi[tid] = bidx;
        __syncthreads();
        for (int s = 128; s > 0; s >>= 1) {
            if (tid < s) {
                float ov = bv[tid + s]; int oi = bi[tid + s];
                if (ov > bv[tid] || (ov == bv[tid] && oi < bi[tid])) { bv[tid] = ov; bi[tid] = oi; }
            }
            __syncthreads();
        }
        const int win = bi[0];
        if (tid == 0) out_idx[row] = (float)win;
        if (tid < 32) {
            float4 ev = *(const float4*)(embed + (size_t)win * D + tid * 4);
            *(float4*)(out_q + row * D + tid * 4) = ev;
        }
        __syncthreads();
    }
}

extern "C" void kernel_launch(void* const* d_in, const int* in_sizes, int n_in,
                              void* d_out, int out_size, void* d_ws, size_t ws_size,
                              hipStream_t stream) {
    const float* x     = (const float*)d_in[0];
    const float* embed = (const float*)d_in[1];
    const int N = in_sizes[0] / D;   // 131072
    char* ws = (char*)d_ws;
    float*          ncsq = (float*)(ws + WS_NCSQ);
    unsigned short* ehi  = (unsigned short*)(ws + WS_EHI);
    float*          embT = (float*)(ws + WS_EMBT);
    float* out_idx = (float*)d_out;
    float* out_q   = out_idx + N;

    hipLaunchKernelGGL(ecb_prep, dim3(64), dim3(256), 0, stream,
                       embed, ncsq, ehi, embT);
    hipLaunchKernelGGL(ecb_main, dim3(N / ROWS_BLK), dim3(256), 0, stream,
                       x, ehi, ncsq, embed, embT, out_idx, out_q);
}

// Round 6
// 281.854 us; speedup vs baseline: 1.0355x; 1.0355x over previous
//
#include <hip/hip_runtime.h>
#include <math.h>

// EuclideanCodebook: N=131072 rows x d=128 fp32, K=1024 codes.
// bf16x3 split-precision MFMA (xh*eh + xl*eh + xh*el), per-row top-2 gap
// tracking, exact fp32 recheck of rows with gap < TAU.
// R2/R8: 64 rows/wave -> spills. 32 rows/wave only.
// R3: dynamic ah[s] indexing -> cndmask waterfall. full s-unroll.
// R6: no-LDS B loads: 174 us (no prefetch distance). REVERTED.
// R7: counted vmcnt + raw barriers + setprio: 156 us vs R0's 146 -- the
//     hand-pinned schedule LOSES to plain __syncthreads. REVERTED.
// R9: bf16x2 + TAU=0.25: 226 us. ~3% rows flagged x 512KB L2 re-read each
//     ~= 55 us recheck tail + latency-bound loop. bf16x2 REVERTED for good.
// R10 (this round): R0 base (best measured, 146 us) + three scoped changes:
//     (a) TWO tiles per sync period: one __syncthreads drain per 48 MFMA
//         (was 24) -- halves the dominant stall class, doubles prefetch
//         distance; LDS 70 KB, same 2 blocks/CU residency.
//     (b) epilogue 5->4 ops/score: x prescaled by 2, accA init = -||e||^2,
//         v_med3_f32 tracks 2nd-best (med3(best_old, v2, cand)).
//     (c) embT dropped; fused recheck reads embed row-major directly
//         (k-sequential fp32 per code preserved -- verified order).

typedef __attribute__((ext_vector_type(8)))  short short8_t;   // 8 bf16
typedef __attribute__((ext_vector_type(16))) float floatx16;   // 32x32 C frag

constexpr int D        = 128;
constexpr int KCODES   = 1024;
constexpr int NTILES   = 32;      // 1024 / 32 codes-per-tile
constexpr int NPAIRS   = 16;      // 2 tiles per sync period
constexpr int ROWS_BLK = 128;     // 4 waves x 32 rows
constexpr float TAU    = 0.015f;  // >> 5-sigma bf16x3 score error (~2e-3)

// ws layout (bytes); total ~0.52 MB
constexpr size_t WS_NCSQ = 0;                      // 1024 f32, NEGATED ||e||^2
constexpr size_t WS_EHI  = 4096;                   // 1024*128 ushort, frag-ordered
constexpr size_t WS_ELO  = WS_EHI + 262144;

#define GLOBAL_AS __attribute__((address_space(1)))
#define LDS_AS    __attribute__((address_space(3)))

__device__ inline unsigned short bf16_rne(float v, float* back) {
    unsigned u = __float_as_uint(v);
    unsigned r = (u + 0x7FFFu + ((u >> 16) & 1u)) >> 16;
    *back = __uint_as_float(r << 16);
    return (unsigned short)r;
}

// ------- prep: ncsq + frag-ordered bf16 hi/lo codebook -------
// 64 blocks x 256 threads; thread = (code n, dim-chunk cc of 8 elements).
// Frag order: short8 chunk index = (t*8 + (cc>>1))*64 + (cc&1)*32 + (n&31),
// so main's lane l reads tile t, MFMA-step s at short8 index (t*8+s)*64 + l.
__global__ __launch_bounds__(256)
void ecb_prep(const float* __restrict__ embed, float* __restrict__ ncsq,
              unsigned short* __restrict__ ehi, unsigned short* __restrict__ elo) {
    const int tid = threadIdx.x;
    const int cc = tid & 15;            // dim chunk 0..15
    const int nl = tid >> 4;            // 0..15
    const int n  = blockIdx.x * 16 + nl;
    const int t = n >> 5, nn = n & 31;
    const float* src = embed + (size_t)n * D + cc * 8;
    float4 a = *(const float4*)src;
    float4 b = *(const float4*)(src + 4);
    float vv[8] = {a.x, a.y, a.z, a.w, b.x, b.y, b.z, b.w};
    float ss = 0.f;
    unsigned short hq[8], lq[8];
#pragma unroll
    for (int j = 0; j < 8; ++j) {
        ss = fmaf(vv[j], vv[j], ss);
        float hb, db;
        hq[j] = bf16_rne(vv[j], &hb);
        lq[j] = bf16_rne(vv[j] - hb, &db);
    }
    uint4 ph, pl;
    ph.x = (unsigned)hq[0] | ((unsigned)hq[1] << 16);
    ph.y = (unsigned)hq[2] | ((unsigned)hq[3] << 16);
    ph.z = (unsigned)hq[4] | ((unsigned)hq[5] << 16);
    ph.w = (unsigned)hq[6] | ((unsigned)hq[7] << 16);
    pl.x = (unsigned)lq[0] | ((unsigned)lq[1] << 16);
    pl.y = (unsigned)lq[2] | ((unsigned)lq[3] << 16);
    pl.z = (unsigned)lq[4] | ((unsigned)lq[5] << 16);
    pl.w = (unsigned)lq[6] | ((unsigned)lq[7] << 16);
    size_t dst = ((size_t)(t * 8 + (cc >> 1)) * 64 + (size_t)((cc & 1) * 32 + nn)) * 8;
    *(uint4*)(ehi + dst) = ph;
    *(uint4*)(elo + dst) = pl;
    // csq reduce over the 16 cc-lanes (contiguous within the wave)
#pragma unroll
    for (int m = 1; m < 16; m <<= 1) ss += __shfl_xor(ss, m, 64);
    if (cc == 0) ncsq[n] = -ss;
}

// ---------------- main: MFMA scores + argmax + fused exact recheck ----------------
__global__ __launch_bounds__(256, 2)
void ecb_main(const float* __restrict__ x,
              const unsigned short* __restrict__ ehi, const unsigned short* __restrict__ elo,
              const float* __restrict__ ncsq, const float* __restrict__ embed,
              float* __restrict__ out_idx, float* __restrict__ out_q) {
    __shared__ short8_t ebuf[2][2][2][512];   // [dbuf][tile-in-pair][hi/lo], 64 KB
    __shared__ float ncsq_s[KCODES];          // 4 KB
    __shared__ int   sidx[ROWS_BLK];
    __shared__ unsigned char llist[ROWS_BLK];
    __shared__ unsigned lcount;

    const int tid  = threadIdx.x;
    const int lane = tid & 63, wave = tid >> 6;
    const int col  = lane & 31, h = lane >> 5;
    const long rowblk = (long)blockIdx.x * ROWS_BLK;
    const int  roww   = wave * 32;

    if (tid == 0) lcount = 0u;

    // stage one PAIR of tiles (2p, 2p+1), hi+lo: 8 global_load_lds per wave
    auto stage = [&](int p, int bb) {
#pragma unroll
        for (int tt = 0; tt < 2; ++tt) {
            const char* gh = (const char*)ehi + (size_t)(2 * p + tt) * 8192;
            const char* gl = (const char*)elo + (size_t)(2 * p + tt) * 8192;
            char* lh = (char*)&ebuf[bb][tt][0][0];
            char* ll = (char*)&ebuf[bb][tt][1][0];
            const int off = wave * 2048;
            __builtin_amdgcn_global_load_lds((const GLOBAL_AS unsigned int*)(gh + off + lane * 16),
                                             (LDS_AS unsigned int*)(lh + off), 16, 0, 0);
            __builtin_amdgcn_global_load_lds((const GLOBAL_AS unsigned int*)(gh + off + 1024 + lane * 16),
                                             (LDS_AS unsigned int*)(lh + off + 1024), 16, 0, 0);
            __builtin_amdgcn_global_load_lds((const GLOBAL_AS unsigned int*)(gl + off + lane * 16),
                                             (LDS_AS unsigned int*)(ll + off), 16, 0, 0);
            __builtin_amdgcn_global_load_lds((const GLOBAL_AS unsigned int*)(gl + off + 1024 + lane * 16),
                                             (LDS_AS unsigned int*)(ll + off + 1024), 16, 0, 0);
        }
    };

    stage(0, 0);                           // issue pair 0 ASAP
    ((float4*)ncsq_s)[tid] = ((const float4*)ncsq)[tid];   // 1024 f32 -> LDS

    // A prologue: 32 rows/wave of x -> bf16 hi/lo split of (2*x) in registers.
    short8_t ah[8], al[8];
    {
        const float* xr = x + (rowblk + roww + col) * (long)D + h * 8;
#pragma unroll
        for (int c = 0; c < 8; ++c) {
            float4 a  = *(const float4*)(xr + c * 16);
            float4 b  = *(const float4*)(xr + c * 16 + 4);
            float vv[8] = {a.x, a.y, a.z, a.w, b.x, b.y, b.z, b.w};
            short8_t fh, fl;
#pragma unroll
            for (int j = 0; j < 8; ++j) {
                float v2x = vv[j] + vv[j];    // fold the score's factor-2 into A
                float hb, db;
                fh[j] = (short)bf16_rne(v2x, &hb);
                fl[j] = (short)bf16_rne(v2x - hb, &db);
            }
            ah[c] = fh;
            al[c] = fl;
        }
    }

    float v1[16], v2[16];
#pragma unroll
    for (int j = 0; j < 16; ++j) { v1[j] = -INFINITY; v2[j] = -INFINITY; }

    __syncthreads();   // pair 0 staged, ncsq_s + lcount visible

#pragma unroll 1
    for (int p = 0; p < NPAIRS; ++p) {
        const int b = p & 1;
        if (p + 1 < NPAIRS) stage(p + 1, b ^ 1);   // prefetch next pair

#pragma unroll
        for (int tt = 0; tt < 2; ++tt) {
            const int t = 2 * p + tt;
            const float negcs = ncsq_s[t * 32 + col];   // LDS, conflict-free

            floatx16 accA, accB;            // acc init = -||e||^2 (A-chain)
#pragma unroll
            for (int i = 0; i < 16; ++i) { accA[i] = negcs; accB[i] = 0.f; }

#pragma unroll
            for (int s = 0; s < 8; ++s) {
                short8_t bh = ebuf[b][tt][0][s * 64 + lane];   // ds_read_b128
                short8_t bl = ebuf[b][tt][1][s * 64 + lane];
                accA = __builtin_amdgcn_mfma_f32_32x32x16_bf16(ah[s], bh, accA, 0, 0, 0);
                accB = __builtin_amdgcn_mfma_f32_32x32x16_bf16(al[s], bh, accB, 0, 0, 0);
                accB = __builtin_amdgcn_mfma_f32_32x32x16_bf16(ah[s], bl, accB, 0, 0, 0);
            }

            // epilogue: 4 VALU/score = add, tag(and_or), max, med3
#pragma unroll
            for (int j = 0; j < 16; ++j) {
                float sc = accA[j] + accB[j];                // 2 x.e - ||e||^2
                unsigned u = (__float_as_uint(sc) & ~31u) | (unsigned)t;
                float cand = __uint_as_float(u);
                float vo = v1[j];
                v1[j] = fmaxf(vo, cand);
                v2[j] = __builtin_amdgcn_fmed3f(vo, v2[j], cand);  // 2nd-best
            }
        }
        __syncthreads();   // drains prefetch + frees buf b (R0 semantics, half rate)
    }

    // cross-lane top-2 merge over the 32 columns of each half
#pragma unroll
    for (int j = 0; j < 16; ++j) {
        float a1 = v1[j], a2 = v2[j];
        int   c1 = (int)((__float_as_uint(a1) & 31u) << 5) | col;   // tile*32 + col
#pragma unroll
        for (int m = 1; m < 32; m <<= 1) {
            float o1 = __shfl_xor(a1, m, 64);
            int   oc = __shfl_xor(c1, m, 64);
            float o2 = __shfl_xor(a2, m, 64);
            float lo = fminf(a1, o1);
            if (o1 > a1) { a1 = o1; c1 = oc; }
            a2 = fmaxf(fmaxf(a2, o2), lo);
        }
        if (col == j) {
            int row_local = roww + (j & 3) + 8 * (j >> 2) + 4 * h;
            sidx[row_local] = c1;
            out_idx[rowblk + row_local] = (float)c1;
            if (a1 - a2 < TAU) {                      // ties always land here
                unsigned p2 = atomicAdd(&lcount, 1u); // <= 128 by construction
                llist[p2] = (unsigned char)row_local;
            }
        }
    }
    __syncthreads();

    // gather quantize = embed[best] (exact fp32 values, L2-hot)
    for (int i = tid; i < ROWS_BLK * 32; i += 256) {
        int r = i >> 5, q = i & 31;
        int code = sidx[r];
        float4 ev = *(const float4*)(embed + (size_t)code * D + q * 4);
        *(float4*)(out_q + (rowblk + r) * (long)D + q * 4) = ev;
    }
    __syncthreads();

    // fused exact fp32 recheck of flagged rows (~0.2/block at TAU=0.015).
    // Reads embed row-major; per-code k-sequential fma order (verified vs ref).
    float* xs = (float*)&ebuf[0][0][0][0];        // 128 f32 (aliases ebuf)
    float* bv = xs + D;                           // 256 f32
    int*   bi = (int*)(bv + 256);                 // 256 i32
    const unsigned nf = lcount;
    for (unsigned f = 0; f < nf; ++f) {
        const int rl  = llist[f];
        const long row = rowblk + rl;
        if (tid < 32) *(float4*)&xs[tid * 4] = *(const float4*)(x + row * D + tid * 4);
        __syncthreads();
        const int c0 = tid * 4;
        float s0 = 0.f, s1 = 0.f, s2 = 0.f, s3 = 0.f;   // 4 codes/thread
#pragma unroll 4
        for (int kc = 0; kc < 32; ++kc) {
            float4 xv = *(const float4*)&xs[kc * 4];
            float4 e0 = *(const float4*)(embed + (size_t)(c0 + 0) * D + kc * 4);
            float4 e1 = *(const float4*)(embed + (size_t)(c0 + 1) * D + kc * 4);
            float4 e2 = *(const float4*)(embed + (size_t)(c0 + 2) * D + kc * 4);
            float4 e3 = *(const float4*)(embed + (size_t)(c0 + 3) * D + kc * 4);
            s0 = fmaf(xv.x, e0.x, s0); s0 = fmaf(xv.y, e0.y, s0);
            s0 = fmaf(xv.z, e0.z, s0); s0 = fmaf(xv.w, e0.w, s0);
            s1 = fmaf(xv.x, e1.x, s1); s1 = fmaf(xv.y, e1.y, s1);
            s1 = fmaf(xv.z, e1.z, s1); s1 = fmaf(xv.w, e1.w, s1);
            s2 = fmaf(xv.x, e2.x, s2); s2 = fmaf(xv.y, e2.y, s2);
            s2 = fmaf(xv.z, e2.z, s2); s2 = fmaf(xv.w, e2.w, s2);
            s3 = fmaf(xv.x, e3.x, s3); s3 = fmaf(xv.y, e3.y, s3);
            s3 = fmaf(xv.z, e3.z, s3); s3 = fmaf(xv.w, e3.w, s3);
        }
        float scs[4] = {fmaf(2.f, s0, ncsq_s[c0]),
                        fmaf(2.f, s1, ncsq_s[c0 + 1]),
                        fmaf(2.f, s2, ncsq_s[c0 + 2]),
                        fmaf(2.f, s3, ncsq_s[c0 + 3])};
        float best = -INFINITY; int bidx = 0;
#pragma unroll
        for (int i = 0; i < 4; ++i)
            if (scs[i] > best) { best = scs[i]; bidx = c0 + i; }
        bv[tid] = best; bi[tid] = bidx;
        __syncthreads();
        for (int s = 128; s > 0; s >>= 1) {
            if (tid < s) {
                float ov = bv[tid + s]; int oi = bi[tid + s];
                if (ov > bv[tid] || (ov == bv[tid] && oi < bi[tid])) { bv[tid] = ov; bi[tid] = oi; }
            }
            __syncthreads();
        }
        const int win = bi[0];
        if (tid == 0) out_idx[row] = (float)win;
        if (tid < 32) {
            float4 ev = *(const float4*)(embed + (size_t)win * D + tid * 4);
            *(float4*)(out_q + row * D + tid * 4) = ev;
        }
        __syncthreads();
    }
}

extern "C" void kernel_launch(void* const* d_in, const int* in_sizes, int n_in,
                              void* d_out, int out_size, void* d_ws, size_t ws_size,
                              hipStream_t stream) {
    const float* x     = (const float*)d_in[0];
    const float* embed = (const float*)d_in[1];
    const int N = in_sizes[0] / D;   // 131072
    char* ws = (char*)d_ws;
    float*          ncsq = (float*)(ws + WS_NCSQ);
    unsigned short* ehi  = (unsigned short*)(ws + WS_EHI);
    unsigned short* elo  = (unsigned short*)(ws + WS_ELO);
    float* out_idx = (float*)d_out;
    float* out_q   = out_idx + N;

    hipLaunchKernelGGL(ecb_prep, dim3(64), dim3(256), 0, stream,
                       embed, ncsq, ehi, elo);
    hipLaunchKernelGGL(ecb_main, dim3(N / ROWS_BLK), dim3(256), 0, stream,
                       x, ehi, elo, ncsq, embed, out_idx, out_q);
}

// Round 7
// 239.153 us; speedup vs baseline: 1.2204x; 1.1786x over previous
//
#include <hip/hip_runtime.h>
#include <math.h>

// EuclideanCodebook: N=131072 rows x d=128 fp32, K=1024 codes.
// bf16x3 split-precision MFMA (xh*eh + xl*eh + xh*el), per-row top-2 gap
// tracking, exact fp32 recheck of rows with gap < TAU.
// Session ledger (measured, main-kernel dur):
//   R0  141 us  32-rows/wave, 2-dbuf LDS staging, plain __syncthreads  <- BEST
//   R6  174 us  no-LDS direct-global B (no prefetch distance)          REVERT
//   R7  156 us  counted vmcnt + raw barriers + setprio                 REVERT
//   R8  177 us  64 rows/wave -> VGPR spill (WRITE +48GB)               REVERT
//   R9  226 us  bf16x2 + TAU=0.25 -> 3% flagged x 512KB L2 rescan      REVERT
//   R10 235 us  tile-pair staging -> 70KB LDS -> occupancy 21->13%     REVERT
// R11 (this round): R0 VERBATIM structure + only correctness-proven,
//   zero-structural-risk deltas:
//   (a) epilogue 6->4 VALU/score: x prescaled by 2 (exact), accA init
//       = -||e||^2, v_med3_f32 2nd-best (all proven in R9b/R10 runs);
//   (b) recheck fused into main tail (R9b-proven, block-local list) ->
//       2 launches, no global counter/list;
//   (c) stage(0) issued before the A-prologue (free prefetch distance);
//   (d) everything else byte-identical to R0: swizzled ehi/elo layout,
//       33 KB LDS, launch_bounds(256,3), plain __syncthreads per tile.

typedef __attribute__((ext_vector_type(8)))  short short8_t;   // 8 bf16
typedef __attribute__((ext_vector_type(16))) float floatx16;   // 32x32 C frag

constexpr int D        = 128;
constexpr int KCODES   = 1024;
constexpr int NTILES   = 32;      // 1024 / 32 codes-per-tile
constexpr int ROWS_BLK = 128;     // 4 waves x 32 rows
constexpr float TAU    = 0.015f;  // >> 5-sigma bf16x3 score error (~2e-3)

// ws layout (bytes); total ~1.05 MB
constexpr size_t WS_NCSQ = 0;                      // 1024 f32, NEGATED ||e||^2
constexpr size_t WS_EHI  = 4096;                   // 1024*128 ushort, swizzled
constexpr size_t WS_ELO  = WS_EHI + 262144;
constexpr size_t WS_EMBT = WS_ELO + 262144;        // 128*1024 f32 transposed

#define GLOBAL_AS __attribute__((address_space(1)))
#define LDS_AS    __attribute__((address_space(3)))

__device__ inline unsigned short bf16_rne(float v, float* back) {
    unsigned u = __float_as_uint(v);
    unsigned r = (u + 0x7FFFu + ((u >> 16) & 1u)) >> 16;
    *back = __uint_as_float(r << 16);
    return (unsigned short)r;
}

// ------- prep: ncsq + swizzled bf16 hi/lo codebook + transposed codebook -------
// R0-verbatim (16 blocks x 64 threads) except csq stored NEGATED, counter gone.
__global__ void ecb_prep(const float* __restrict__ embed, float* __restrict__ ncsq,
                         unsigned short* __restrict__ ehi, unsigned short* __restrict__ elo,
                         float* __restrict__ embT) {
    int n = blockIdx.x * 64 + threadIdx.x;
    if (n >= KCODES) return;
    const int t = n >> 5, nn = n & 31, nm = nn & 15;
    const float* row = embed + (size_t)n * D;
    const size_t tb = (size_t)t * 32 * D + (size_t)nn * D;
    float s = 0.f;
#pragma unroll
    for (int cc = 0; cc < 16; ++cc) {
        float4 a  = *(const float4*)(row + cc * 8);
        float4 bq = *(const float4*)(row + cc * 8 + 4);
        s = fmaf(a.x, a.x, s);  s = fmaf(a.y, a.y, s);
        s = fmaf(a.z, a.z, s);  s = fmaf(a.w, a.w, s);
        s = fmaf(bq.x, bq.x, s); s = fmaf(bq.y, bq.y, s);
        s = fmaf(bq.z, bq.z, s); s = fmaf(bq.w, bq.w, s);
        float vv[8] = {a.x, a.y, a.z, a.w, bq.x, bq.y, bq.z, bq.w};
#pragma unroll
        for (int j = 0; j < 8; ++j) embT[(size_t)(cc * 8 + j) * KCODES + n] = vv[j];
        unsigned short h[8], l[8];
#pragma unroll
        for (int j = 0; j < 8; ++j) {
            float hb, db;
            h[j] = bf16_rne(vv[j], &hb);
            l[j] = bf16_rne(vv[j] - hb, &db);
        }
        uint4 ph, pl;
        ph.x = (unsigned)h[0] | ((unsigned)h[1] << 16);
        ph.y = (unsigned)h[2] | ((unsigned)h[3] << 16);
        ph.z = (unsigned)h[4] | ((unsigned)h[5] << 16);
        ph.w = (unsigned)h[6] | ((unsigned)h[7] << 16);
        pl.x = (unsigned)l[0] | ((unsigned)l[1] << 16);
        pl.y = (unsigned)l[2] | ((unsigned)l[3] << 16);
        pl.z = (unsigned)l[4] | ((unsigned)l[5] << 16);
        pl.w = (unsigned)l[6] | ((unsigned)l[7] << 16);
        // XOR swizzle on the 16B chunk index -> conflict-free ds_read_b128 later
        size_t dst = tb + (size_t)((cc ^ nm) * 8);
        *(uint4*)(ehi + dst) = ph;
        *(uint4*)(elo + dst) = pl;
    }
    ncsq[n] = -s;
}

// ---------------- main: MFMA scores + argmax + fused exact recheck ----------------
__global__ __launch_bounds__(256, 3)
void ecb_main(const float* __restrict__ x,
              const unsigned short* __restrict__ ehi, const unsigned short* __restrict__ elo,
              const float* __restrict__ ncsq, const float* __restrict__ embed,
              const float* __restrict__ embT,
              float* __restrict__ out_idx, float* __restrict__ out_q) {
    __shared__ unsigned short ebuf[2][2][4096];   // [dbuf][hi/lo][32 codes x 128], 32 KB
    __shared__ int sidx[ROWS_BLK];                // 512 B
    __shared__ unsigned char llist[ROWS_BLK];
    __shared__ unsigned lcount;

    const int tid  = threadIdx.x;
    const int lane = tid & 63, wave = tid >> 6;
    const int col  = lane & 31, h = lane >> 5, colm = col & 15;
    const long rowblk = (long)blockIdx.x * ROWS_BLK;
    const int  roww   = wave * 32;

    if (tid == 0) lcount = 0u;

    auto stage = [&](int t, int b) {
        const char* gh = (const char*)(ehi) + (size_t)t * 8192;
        const char* gl = (const char*)(elo) + (size_t)t * 8192;
        char* lh = (char*)&ebuf[b][0][0];
        char* ll = (char*)&ebuf[b][1][0];
#pragma unroll
        for (int i = 0; i < 2; ++i) {
            int off = i * 4096 + wave * 1024;
            __builtin_amdgcn_global_load_lds((const GLOBAL_AS unsigned int*)(gh + off + lane * 16),
                                             (LDS_AS unsigned int*)(lh + off), 16, 0, 0);
            __builtin_amdgcn_global_load_lds((const GLOBAL_AS unsigned int*)(gl + off + lane * 16),
                                             (LDS_AS unsigned int*)(ll + off), 16, 0, 0);
        }
    };

    stage(0, 0);   // issued BEFORE the A-prologue: DMA overlaps x-load+cvt

    // A prologue: 32 rows/wave of x -> bf16 hi/lo split of (2*x) in registers.
    short8_t ah[8], al[8];
    {
        const float* xr = x + (rowblk + roww + col) * (long)D + h * 8;
#pragma unroll
        for (int c = 0; c < 8; ++c) {
            float4 a  = *(const float4*)(xr + c * 16);
            float4 bq = *(const float4*)(xr + c * 16 + 4);
            float vv[8] = {a.x, a.y, a.z, a.w, bq.x, bq.y, bq.z, bq.w};
            short8_t fh, fl;
#pragma unroll
            for (int j = 0; j < 8; ++j) {
                float v2x = vv[j] + vv[j];    // exact: split of 2x == 2*split of x
                float hb, db;
                fh[j] = (short)bf16_rne(v2x, &hb);
                fl[j] = (short)bf16_rne(v2x - hb, &db);
            }
            ah[c] = fh;
            al[c] = fl;
        }
    }

    float v1[16], v2[16];
#pragma unroll
    for (int j = 0; j < 16; ++j) { v1[j] = -INFINITY; v2[j] = -INFINITY; }

    __syncthreads();

#pragma unroll 1
    for (int t = 0; t < NTILES; ++t) {
        const int b = t & 1;
        if (t + 1 < NTILES) stage(t + 1, (t + 1) & 1);

        const float negcs = ncsq[t * 32 + col];   // L1-hot 4 KB table

        floatx16 accA, accB;   // accA init = -||e||^2; 2 independent chains
#pragma unroll
        for (int i = 0; i < 16; ++i) { accA[i] = negcs; accB[i] = 0.f; }

        // FULL unroll: constant indices keep ah[s]/al[s] in registers (R3 bug).
#pragma unroll
        for (int s = 0; s < 8; ++s) {
            const int cc = 2 * s + h;
            const int idx = (col * 16 + (cc ^ colm)) * 8;   // elements
            short8_t bh = *(const short8_t*)&ebuf[b][0][idx];
            short8_t bl = *(const short8_t*)&ebuf[b][1][idx];
            accA = __builtin_amdgcn_mfma_f32_32x32x16_bf16(ah[s], bh, accA, 0, 0, 0);
            accB = __builtin_amdgcn_mfma_f32_32x32x16_bf16(al[s], bh, accB, 0, 0, 0);
            accB = __builtin_amdgcn_mfma_f32_32x32x16_bf16(ah[s], bl, accB, 0, 0, 0);
        }

        // epilogue: score = 2x.e - ||e||^2 already; 4 VALU/score
#pragma unroll
        for (int j = 0; j < 16; ++j) {
            float sc = accA[j] + accB[j];
            unsigned u = (__float_as_uint(sc) & ~31u) | (unsigned)t;
            float cand = __uint_as_float(u);
            float vo = v1[j];
            v1[j] = fmaxf(vo, cand);
            v2[j] = __builtin_amdgcn_fmed3f(vo, v2[j], cand);  // 2nd-best
        }
        __syncthreads();
    }

    // cross-lane top-2 merge over the 32 columns of each half
#pragma unroll
    for (int j = 0; j < 16; ++j) {
        float a1 = v1[j], a2 = v2[j];
        int   c1 = (int)((__float_as_uint(a1) & 31u) << 5) | col;   // tile*32 + col
#pragma unroll
        for (int m = 1; m < 32; m <<= 1) {
            float o1 = __shfl_xor(a1, m, 64);
            int   oc = __shfl_xor(c1, m, 64);
            float o2 = __shfl_xor(a2, m, 64);
            float lo = fminf(a1, o1);
            if (o1 > a1) { a1 = o1; c1 = oc; }
            a2 = fmaxf(fmaxf(a2, o2), lo);
        }
        if (col == j) {
            int row_local = roww + (j & 3) + 8 * (j >> 2) + 4 * h;
            sidx[row_local] = c1;
            out_idx[rowblk + row_local] = (float)c1;
            if (a1 - a2 < TAU) {                      // ties always land here
                unsigned p = atomicAdd(&lcount, 1u);  // <= 128 by construction
                llist[p] = (unsigned char)row_local;
            }
        }
    }
    __syncthreads();

    // gather quantize = embed[best] (exact fp32 values, L2-hot)
    for (int i = tid; i < ROWS_BLK * 32; i += 256) {
        int r = i >> 5, q = i & 31;
        int code = sidx[r];
        float4 ev = *(const float4*)(embed + (size_t)code * D + q * 4);
        *(float4*)(out_q + (rowblk + r) * (long)D + q * 4) = ev;
    }
    __syncthreads();

    // fused exact fp32 recheck of this block's flagged rows (~0.2/block at
    // TAU=0.015). R9b-proven code; coalesced embT reads; scratch aliases ebuf.
    float* xs = (float*)&ebuf[0][0][0];           // 128 f32
    float* bv = xs + D;                           // 256 f32
    int*   bi = (int*)(bv + 256);                 // 256 i32
    const unsigned nf = lcount;
    const float4* eT = (const float4*)embT;       // [k][256 x float4-of-codes]
    for (unsigned f = 0; f < nf; ++f) {
        const int rl  = llist[f];
        const long row = rowblk + rl;
        if (tid < 32) *(float4*)&xs[tid * 4] = *(const float4*)(x + row * D + tid * 4);
        __syncthreads();
        float4 dot = {0.f, 0.f, 0.f, 0.f};
#pragma unroll 8
        for (int k = 0; k < D; ++k) {
            float xv = xs[k];
            float4 e = eT[(size_t)k * 256 + tid];
            dot.x = fmaf(xv, e.x, dot.x);
            dot.y = fmaf(xv, e.y, dot.y);
            dot.z = fmaf(xv, e.z, dot.z);
            dot.w = fmaf(xv, e.w, dot.w);
        }
        const int c0 = tid * 4;
        float4 nc = *(const float4*)(ncsq + c0);
        float scs[4] = {fmaf(2.f, dot.x, nc.x),
                        fmaf(2.f, dot.y, nc.y),
                        fmaf(2.f, dot.z, nc.z),
                        fmaf(2.f, dot.w, nc.w)};
        float best = -INFINITY; int bidx = 0;
#pragma unroll
        for (int i = 0; i < 4; ++i)
            if (scs[i] > best) { best = scs[i]; bidx = c0 + i; }
        bv[tid] = best; bi[tid] = bidx;
        __syncthreads();
        for (int s = 128; s > 0; s >>= 1) {
            if (tid < s) {
                float ov = bv[tid + s]; int oi = bi[tid + s];
                if (ov > bv[tid] || (ov == bv[tid] && oi < bi[tid])) { bv[tid] = ov; bi[tid] = oi; }
            }
            __syncthreads();
        }
        const int win = bi[0];
        if (tid == 0) out_idx[row] = (float)win;
        if (tid < 32) {
            float4 ev = *(const float4*)(embed + (size_t)win * D + tid * 4);
            *(float4*)(out_q + row * D + tid * 4) = ev;
        }
        __syncthreads();
    }
}

extern "C" void kernel_launch(void* const* d_in, const int* in_sizes, int n_in,
                              void* d_out, int out_size, void* d_ws, size_t ws_size,
                              hipStream_t stream) {
    const float* x     = (const float*)d_in[0];
    const float* embed = (const float*)d_in[1];
    const int N = in_sizes[0] / D;   // 131072
    char* ws = (char*)d_ws;
    float*          ncsq = (float*)(ws + WS_NCSQ);
    unsigned short* ehi  = (unsigned short*)(ws + WS_EHI);
    unsigned short* elo  = (unsigned short*)(ws + WS_ELO);
    float*          embT = (float*)(ws + WS_EMBT);
    float* out_idx = (float*)d_out;
    float* out_q   = out_idx + N;

    hipLaunchKernelGGL(ecb_prep, dim3(16), dim3(64), 0, stream,
                       embed, ncsq, ehi, elo, embT);
    hipLaunchKernelGGL(ecb_main, dim3(N / ROWS_BLK), dim3(256), 0, stream,
                       x, ehi, elo, ncsq, embed, embT, out_idx, out_q);
}